// Round 4
// baseline (1003.104 us; speedup 1.0000x reference)
//
#include <hip/hip_runtime.h>
#include <hip/hip_bf16.h>
#include <stdint.h>

#define T_TOK 4096
#define DIMD  2048
#define NEXP  16
#define TOPK  4
#define NI    1024
#define NSH   2048

typedef __attribute__((ext_vector_type(8))) short short8;
typedef __attribute__((ext_vector_type(4))) float f32x4;
typedef __attribute__((ext_vector_type(4))) unsigned short u16x4;

__device__ __forceinline__ unsigned short f2bf(float f) {
    union { float f; unsigned u; } v; v.f = f;
    return (unsigned short)((v.u + 0x7fffu + ((v.u >> 16) & 1u)) >> 16);
}

__device__ __forceinline__ void gload16(const void* g, void* l) {
    __builtin_amdgcn_global_load_lds(
        (const __attribute__((address_space(1))) void*)g,
        (__attribute__((address_space(3))) void*)l, 16, 0, 0);
}

// ---------------- gate + routing ----------------
__global__ __launch_bounds__(64) void gate_kernel(const float* __restrict__ x,
                                                  const float* __restrict__ gw,
                                                  int* __restrict__ cnt,
                                                  int* __restrict__ list,
                                                  float* __restrict__ cw) {
    int t = blockIdx.x;
    int lane = threadIdx.x;
    float acc[NEXP];
#pragma unroll
    for (int e = 0; e < NEXP; ++e) acc[e] = 0.f;
    const float* xr = x + (size_t)t * DIMD;
    for (int d0 = 0; d0 < DIMD; d0 += 64) {
        int d = d0 + lane;
        float xv = xr[d];
        const f32x4* g = (const f32x4*)(gw + (size_t)d * NEXP);
#pragma unroll
        for (int q = 0; q < 4; ++q) {
            f32x4 gv = g[q];
#pragma unroll
            for (int j = 0; j < 4; ++j) acc[q * 4 + j] += xv * gv[j];
        }
    }
#pragma unroll
    for (int e = 0; e < NEXP; ++e) {
        float v = acc[e];
#pragma unroll
        for (int off = 32; off; off >>= 1) v += __shfl_xor(v, off, 64);
        acc[e] = v;
    }
    float m = acc[0];
#pragma unroll
    for (int e = 1; e < NEXP; ++e) m = fmaxf(m, acc[e]);
    float s = 0.f;
#pragma unroll
    for (int e = 0; e < NEXP; ++e) { acc[e] = expf(acc[e] - m); s += acc[e]; }
    float inv = 1.f / s;
#pragma unroll
    for (int e = 0; e < NEXP; ++e) acc[e] *= inv;

    if (lane == 0) {
        bool used[NEXP];
#pragma unroll
        for (int e = 0; e < NEXP; ++e) used[e] = false;
        for (int k = 0; k < TOPK; ++k) {
            int be = 0; float bv = -1.f;
            for (int e = 0; e < NEXP; ++e)
                if (!used[e] && acc[e] > bv) { bv = acc[e]; be = e; }
            used[be] = true;
            int r = atomicAdd(&cnt[be], 1);
            list[be * T_TOK + r] = t;
            cw[be * T_TOK + r] = bv;
        }
    }
}

__global__ void scan_kernel(const int* __restrict__ cnt, int* __restrict__ offs) {
    if (threadIdx.x == 0) {
        int o = 0;
        for (int e = 0; e < NEXP; ++e) { offs[e] = o; o += cnt[e]; }
        offs[NEXP] = o;
    }
}

// ---------------- x fp32 -> bf16 ----------------
__global__ __launch_bounds__(256) void cvt_kernel(const float* __restrict__ x,
                                                  unsigned short* __restrict__ xb) {
    int i = blockIdx.x * 256 + threadIdx.x;
    const f32x4* src = (const f32x4*)x;
    f32x4 a = src[i * 2 + 0];
    f32x4 b = src[i * 2 + 1];
    short8 o;
#pragma unroll
    for (int j = 0; j < 4; ++j) o[j] = (short)f2bf(a[j]);
#pragma unroll
    for (int j = 0; j < 4; ++j) o[4 + j] = (short)f2bf(b[j]);
    ((short8*)xb)[i] = o;
}

// ---------------- weight transpose + convert ----------------
template <int MODE>
__global__ __launch_bounds__(256) void tq_kernel(const float* __restrict__ src,
                                                 unsigned short* __restrict__ dst,
                                                 int K, int N, size_t dstStrideE) {
    int e = blockIdx.z;
    src += (size_t)e * K * N;
    dst += (size_t)e * dstStrideE;
    __shared__ unsigned short tile[32][36];
    int t = threadIdx.x;
    int k0 = blockIdx.y * 32, n0 = blockIdx.x * 32;
    {
        int row = t >> 3, c4 = (t & 7) * 4;
        f32x4 v = *(const f32x4*)(src + (size_t)(k0 + row) * N + n0 + c4);
#pragma unroll
        for (int j = 0; j < 4; ++j) tile[row][c4 + j] = f2bf(v[j]);
    }
    __syncthreads();
    {
        int nn = t >> 3, kc = (t & 7) * 4;
        int n = n0 + nn;
        int r = (MODE == 0) ? n : ((n >> 4) * 32 + (MODE == 2 ? 16 : 0) + (n & 15));
        u16x4 o;
#pragma unroll
        for (int j = 0; j < 4; ++j) o[j] = tile[kc + j][nn];
        *(u16x4*)(dst + (size_t)r * K + k0 + kc) = o;
    }
}

// ================= 256x256 8-phase GEMM, fragment-reuse schedule =================
// Per K-tile (64 cols): ph1 read A0+B0, MFMA(0,0) | ph2 read B1, MFMA(0,1)
//                       ph3 read A1, MFMA(1,1)    | ph4 no reads, MFMA(1,0)
// Stage units 4 phases ahead of first read: loads/phase [4,2,2,0], vmcnt [6,6,-,4].

#define STA(u, d, kt) do { \
    gload16(gA[u][0] + (kt) * 64, (void*)(smem + (d) * 65536 + ldsA[u][0])); \
    gload16(gA[u][1] + (kt) * 64, (void*)(smem + (d) * 65536 + ldsA[u][1])); \
  } while (0)
#define STB(u, d, kt) do { \
    gload16(gB[u][0] + (kt) * 64, (void*)(smem + (d) * 65536 + 32768 + ldsB[u][0])); \
    gload16(gB[u][1] + (kt) * 64, (void*)(smem + (d) * 65536 + 32768 + ldsB[u][1])); \
  } while (0)

#define RDA(D, MH) do { \
    _Pragma("unroll") \
    for (int m2 = 0; m2 < 4; ++m2) { \
      const char* bp = smem + (D) * 65536 + (wm * 128 + (MH) * 64 + m2 * 16 + fr) * 128; \
      aF[m2][0] = *(const short8*)(bp + kA0); \
      aF[m2][1] = *(const short8*)(bp + kA1); \
    } } while (0)
#define RDB(dst, D, NH) do { \
    _Pragma("unroll") \
    for (int n2 = 0; n2 < 2; ++n2) { \
      const char* bp = smem + (D) * 65536 + 32768 + (wn * 64 + (NH) * 32 + n2 * 16 + fr) * 128; \
      dst[n2][0] = *(const short8*)(bp + kA0); \
      dst[n2][1] = *(const short8*)(bp + kA1); \
    } } while (0)

#define MM(MH, NH, BF) do { \
    __builtin_amdgcn_s_setprio(1); \
    _Pragma("unroll") \
    for (int m2 = 0; m2 < 4; ++m2) { \
      _Pragma("unroll") \
      for (int n2 = 0; n2 < 2; ++n2) { \
        acc[(MH) * 4 + m2][(NH) * 2 + n2] = __builtin_amdgcn_mfma_f32_16x16x32_bf16( \
            aF[m2][0], BF[n2][0], acc[(MH) * 4 + m2][(NH) * 2 + n2], 0, 0, 0); \
        acc[(MH) * 4 + m2][(NH) * 2 + n2] = __builtin_amdgcn_mfma_f32_16x16x32_bf16( \
            aF[m2][1], BF[n2][1], acc[(MH) * 4 + m2][(NH) * 2 + n2], 0, 0, 0); \
      } \
    } \
    __builtin_amdgcn_s_setprio(0); \
  } while (0)

#define BARMID do { \
    __builtin_amdgcn_s_barrier(); \
    asm volatile("s_waitcnt lgkmcnt(0)" ::: "memory"); \
    __builtin_amdgcn_sched_barrier(0); \
  } while (0)

#define KTILE(D, DN, KT, COND) do { \
    RDA(D, 0); RDB(bF0, D, 0); \
    if (COND) { STA(0, DN, KT); STB(0, DN, KT); } \
    asm volatile("s_waitcnt vmcnt(6)" ::: "memory"); \
    BARMID; \
    MM(0, 0, bF0); \
    __builtin_amdgcn_s_barrier(); \
    RDB(bF1, D, 1); \
    if (COND) STB(1, DN, KT); \
    asm volatile("s_waitcnt vmcnt(6)" ::: "memory"); \
    BARMID; \
    MM(0, 1, bF1); \
    __builtin_amdgcn_s_barrier(); \
    RDA(D, 1); \
    if (COND) STA(1, DN, KT); \
    BARMID; \
    MM(1, 1, bF1); \
    __builtin_amdgcn_s_barrier(); \
    MM(1, 0, bF0); \
    asm volatile("s_waitcnt vmcnt(4)" ::: "memory"); \
    __builtin_amdgcn_s_barrier(); \
  } while (0)

template <int KIND>
__global__ __launch_bounds__(512, 2) void gemm8p(
    const unsigned short* __restrict__ A, const unsigned short* __restrict__ Ball,
    const int* __restrict__ cnt, const int* __restrict__ offs,
    const int* __restrict__ list, const float* __restrict__ cw,
    unsigned short* __restrict__ hout, float* __restrict__ fout) {
    constexpr bool ROUTED = (KIND == 1 || KIND == 3);
    constexpr bool UP = (KIND <= 1);
    constexpr int K = (KIND <= 1) ? 2048 : 1024;
    constexpr int NITER = K / 128;
    constexpr int ASTR = (KIND == 3) ? 1024 : 2048;
    constexpr int BSTR = (KIND == 3) ? 1024 : 2048;

    const int bx = blockIdx.x, by = blockIdx.y;
    const int e = ROUTED ? blockIdx.z : 0;
    const int M = ROUTED ? cnt[e] : T_TOK;
    const int rb = by * 256;
    if (ROUTED && rb >= M) return;
    const int obase = ROUTED ? offs[e] : 0;
    const int kb = (KIND == 2) ? blockIdx.z * 1024 : 0;
    const unsigned short* Bp = Ball +
        (KIND == 1 ? (size_t)e * 2048 * 2048 : KIND == 3 ? (size_t)e * 2048 * 1024 : 0);

    extern __shared__ char smem[];

    const int tid = threadIdx.x;
    const int lane = tid & 63, wid = tid >> 6;
    const int wm = wid >> 2, wn = wid & 3;
    const int fr = lane & 15, fq = lane >> 4;
    const int swz = (fr & 7) << 4;
    const int kA0 = (fq * 16) ^ swz;
    const int kA1 = (64 + fq * 16) ^ swz;

    int ldsA[2][2], ldsB[2][2];
    const unsigned short* gA[2][2];
    const unsigned short* gB[2][2];
#pragma unroll
    for (int u = 0; u < 2; ++u)
#pragma unroll
        for (int i = 0; i < 2; ++i) {
            int rowA = i * 128 + u * 64 + (tid >> 3);
            int kcA = (tid & 7) ^ (rowA & 7);
            ldsA[u][i] = i * 16384 + u * 8192 + tid * 16;
            int gr = rb + rowA;
            int cr = (gr < M) ? gr : (M - 1);
            size_t arow;
            if (KIND == 1)      arow = (size_t)list[e * T_TOK + cr];
            else if (KIND == 3) arow = (size_t)(obase + cr);
            else                arow = (size_t)gr;
            gA[u][i] = A + arow * ASTR + kb + kcA * 8;

            int s = (tid >> 8) + 2 * i;
            int rowB = s * 64 + u * 32 + ((tid >> 3) & 31);
            int kcB = (tid & 7) ^ (rowB & 7);
            ldsB[u][i] = s * 8192 + u * 4096 + (tid & 255) * 16;
            gB[u][i] = Bp + (size_t)(bx * 256 + rowB) * BSTR + kb + kcB * 8;
        }

    f32x4 acc[8][4];
#pragma unroll
    for (int m = 0; m < 8; ++m)
#pragma unroll
        for (int n = 0; n < 4; ++n) acc[m][n] = (f32x4)0.f;

    short8 aF[4][2], bF0[2][2], bF1[2][2];

    // prologue: kt0 (all 4 units) -> d0
    STA(0, 0, 0); STB(0, 0, 0); STB(1, 0, 0); STA(1, 0, 0);
    asm volatile("s_waitcnt vmcnt(0)" ::: "memory");
    __builtin_amdgcn_s_barrier();

    for (int it = 0; it < NITER; ++it) {
        const bool more = (it + 1 < NITER);
        KTILE(0, 1, 2 * it + 1, true);
        KTILE(1, 0, 2 * it + 2, more);
    }

    // epilogue
    if constexpr (UP) {
        constexpr int LDO = (KIND == 1) ? NI : NSH;
#pragma unroll
        for (int mf = 0; mf < 8; ++mf)
#pragma unroll
            for (int q = 0; q < 4; ++q) {
                int gr = rb + wm * 128 + mf * 16 + fq * 4 + q;
                if (gr < M) {
                    float coef = 1.f;
                    if constexpr (KIND == 1) coef = cw[e * T_TOK + gr];
                    size_t orow = (size_t)(obase + gr) * LDO;
#pragma unroll
                    for (int nfp = 0; nfp < 2; ++nfp) {
                        float c1 = acc[mf][2 * nfp][q], c3 = acc[mf][2 * nfp + 1][q];
                        float h = c1 / (1.f + __expf(-c1)) * c3 * coef;
                        int ncol = (bx * 8 + wn * 2 + nfp) * 16 + fr;
                        hout[orow + ncol] = f2bf(h);
                    }
                }
            }
    } else {
#pragma unroll
        for (int mf = 0; mf < 8; ++mf)
#pragma unroll
            for (int q = 0; q < 4; ++q) {
                int gr = rb + wm * 128 + mf * 16 + fq * 4 + q;
                if (gr < M) {
                    int orow = (KIND == 3) ? list[e * T_TOK + gr] : gr;
#pragma unroll
                    for (int nf = 0; nf < 4; ++nf) {
                        int col = bx * 256 + wn * 64 + nf * 16 + fr;
                        atomicAdd(fout + (size_t)orow * DIMD + col, acc[mf][nf][q]);
                    }
                }
            }
    }
}

extern "C" void kernel_launch(void* const* d_in, const int* in_sizes, int n_in,
                              void* d_out, int out_size, void* d_ws, size_t ws_size,
                              hipStream_t stream) {
    const float* x   = (const float*)d_in[0];
    const float* gw  = (const float*)d_in[1];
    const float* w1  = (const float*)d_in[2];
    const float* w2  = (const float*)d_in[3];
    const float* w3  = (const float*)d_in[4];
    const float* ws1 = (const float*)d_in[5];
    const float* ws2 = (const float*)d_in[6];
    const float* ws3 = (const float*)d_in[7];
    float* out = (float*)d_out;

    char* p = (char*)d_ws;
    unsigned short* xb   = (unsigned short*)p; p += (size_t)T_TOK * DIMD * 2;
    unsigned short* hs   = (unsigned short*)p; p += (size_t)T_TOK * NSH * 2;
    unsigned short* hbuf = (unsigned short*)p; p += (size_t)T_TOK * TOPK * NI * 2;
    unsigned short* upT  = (unsigned short*)p; p += (size_t)NEXP * 2048 * DIMD * 2;
    unsigned short* w2T  = (unsigned short*)p; p += (size_t)NEXP * DIMD * NI * 2;
    unsigned short* upsT = (unsigned short*)p; p += (size_t)2 * NSH * DIMD * 2;
    unsigned short* ws2T = (unsigned short*)p; p += (size_t)DIMD * NSH * 2;
    float* cw = (float*)p;                     p += (size_t)NEXP * T_TOK * 4;
    int* list = (int*)p;                       p += (size_t)NEXP * T_TOK * 4;
    int* cnt = (int*)p;                        p += 256;
    int* offs = (int*)p;                       p += 256;
    if ((size_t)(p - (char*)d_ws) > ws_size) return;

    hipFuncSetAttribute((const void*)&gemm8p<0>, hipFuncAttributeMaxDynamicSharedMemorySize, 131072);
    hipFuncSetAttribute((const void*)&gemm8p<1>, hipFuncAttributeMaxDynamicSharedMemorySize, 131072);
    hipFuncSetAttribute((const void*)&gemm8p<2>, hipFuncAttributeMaxDynamicSharedMemorySize, 131072);
    hipFuncSetAttribute((const void*)&gemm8p<3>, hipFuncAttributeMaxDynamicSharedMemorySize, 131072);

    hipMemsetAsync(cnt, 0, 64, stream);
    hipMemsetAsync(out, 0, (size_t)out_size * 4, stream);
    gate_kernel<<<T_TOK, 64, 0, stream>>>(x, gw, cnt, list, cw);
    scan_kernel<<<1, 64, 0, stream>>>(cnt, offs);
    cvt_kernel<<<(T_TOK * DIMD / 8) / 256, 256, 0, stream>>>(x, xb);

    tq_kernel<1><<<dim3(NI / 32, DIMD / 32, NEXP), 256, 0, stream>>>(w1, upT, DIMD, NI, (size_t)2048 * DIMD);
    tq_kernel<2><<<dim3(NI / 32, DIMD / 32, NEXP), 256, 0, stream>>>(w3, upT, DIMD, NI, (size_t)2048 * DIMD);
    tq_kernel<1><<<dim3(NSH / 32, DIMD / 32, 1), 256, 0, stream>>>(ws1, upsT, DIMD, NSH, 0);
    tq_kernel<2><<<dim3(NSH / 32, DIMD / 32, 1), 256, 0, stream>>>(ws3, upsT, DIMD, NSH, 0);
    tq_kernel<0><<<dim3(DIMD / 32, NI / 32, NEXP), 256, 0, stream>>>(w2, w2T, NI, DIMD, (size_t)DIMD * NI);
    tq_kernel<0><<<dim3(DIMD / 32, NSH / 32, 1), 256, 0, stream>>>(ws2, ws2T, NSH, DIMD, 0);

    gemm8p<0><<<dim3(16, 16, 1), 512, 131072, stream>>>(
        xb, upsT, nullptr, nullptr, nullptr, nullptr, hs, nullptr);
    gemm8p<2><<<dim3(8, 16, 2), 512, 131072, stream>>>(
        hs, ws2T, nullptr, nullptr, nullptr, nullptr, nullptr, out);
    gemm8p<1><<<dim3(8, 16, NEXP), 512, 131072, stream>>>(
        xb, upT, cnt, offs, list, cw, hbuf, nullptr);
    gemm8p<3><<<dim3(8, 16, NEXP), 512, 131072, stream>>>(
        hbuf, w2T, cnt, offs, list, nullptr, nullptr, out);
}

// Round 5
// 884.567 us; speedup vs baseline: 1.1340x; 1.1340x over previous
//
#include <hip/hip_runtime.h>
#include <hip/hip_bf16.h>
#include <stdint.h>

#define T_TOK 4096
#define DIMD  2048
#define NEXP  16
#define TOPK  4
#define NI    1024
#define NSH   2048

typedef __attribute__((ext_vector_type(8))) short short8;
typedef __attribute__((ext_vector_type(4))) float f32x4;
typedef __attribute__((ext_vector_type(4))) unsigned short u16x4;

__device__ __forceinline__ unsigned short f2bf(float f) {
    union { float f; unsigned u; } v; v.f = f;
    return (unsigned short)((v.u + 0x7fffu + ((v.u >> 16) & 1u)) >> 16);
}

__device__ __forceinline__ void gload16(const void* g, void* l) {
    __builtin_amdgcn_global_load_lds(
        (const __attribute__((address_space(1))) void*)g,
        (__attribute__((address_space(3))) void*)l, 16, 0, 0);
}

// ---------------- gate + routing ----------------
__global__ __launch_bounds__(64) void gate_kernel(const float* __restrict__ x,
                                                  const float* __restrict__ gw,
                                                  int* __restrict__ cnt,
                                                  int* __restrict__ list,
                                                  float* __restrict__ cw) {
    int t = blockIdx.x;
    int lane = threadIdx.x;
    float acc[NEXP];
#pragma unroll
    for (int e = 0; e < NEXP; ++e) acc[e] = 0.f;
    const float* xr = x + (size_t)t * DIMD;
    for (int d0 = 0; d0 < DIMD; d0 += 64) {
        int d = d0 + lane;
        float xv = xr[d];
        const f32x4* g = (const f32x4*)(gw + (size_t)d * NEXP);
#pragma unroll
        for (int q = 0; q < 4; ++q) {
            f32x4 gv = g[q];
#pragma unroll
            for (int j = 0; j < 4; ++j) acc[q * 4 + j] += xv * gv[j];
        }
    }
#pragma unroll
    for (int e = 0; e < NEXP; ++e) {
        float v = acc[e];
#pragma unroll
        for (int off = 32; off; off >>= 1) v += __shfl_xor(v, off, 64);
        acc[e] = v;
    }
    float m = acc[0];
#pragma unroll
    for (int e = 1; e < NEXP; ++e) m = fmaxf(m, acc[e]);
    float s = 0.f;
#pragma unroll
    for (int e = 0; e < NEXP; ++e) { acc[e] = expf(acc[e] - m); s += acc[e]; }
    float inv = 1.f / s;
#pragma unroll
    for (int e = 0; e < NEXP; ++e) acc[e] *= inv;

    if (lane == 0) {
        bool used[NEXP];
#pragma unroll
        for (int e = 0; e < NEXP; ++e) used[e] = false;
        for (int k = 0; k < TOPK; ++k) {
            int be = 0; float bv = -1.f;
            for (int e = 0; e < NEXP; ++e)
                if (!used[e] && acc[e] > bv) { bv = acc[e]; be = e; }
            used[be] = true;
            int r = atomicAdd(&cnt[be], 1);
            list[be * T_TOK + r] = t;
            cw[be * T_TOK + r] = bv;
        }
    }
}

// offsets + compact tile table: table[s]=expert, table[128+s]=rb, table[255]=nslots
__global__ void scan_kernel(const int* __restrict__ cnt, int* __restrict__ offs,
                            int* __restrict__ table) {
    if (threadIdx.x == 0) {
        int o = 0;
        for (int e = 0; e < NEXP; ++e) { offs[e] = o; o += cnt[e]; }
        offs[NEXP] = o;
        int ns = 0;
        for (int e = 0; e < NEXP; ++e)
            for (int rb = 0; rb < cnt[e]; rb += 256) {
                table[ns] = e; table[128 + ns] = rb; ++ns;
            }
        table[255] = ns;
    }
}

// ---------------- x fp32 -> bf16 ----------------
__global__ __launch_bounds__(256) void cvt_kernel(const float* __restrict__ x,
                                                  unsigned short* __restrict__ xb) {
    int i = blockIdx.x * 256 + threadIdx.x;
    const f32x4* src = (const f32x4*)x;
    f32x4 a = src[i * 2 + 0];
    f32x4 b = src[i * 2 + 1];
    short8 o;
#pragma unroll
    for (int j = 0; j < 4; ++j) o[j] = (short)f2bf(a[j]);
#pragma unroll
    for (int j = 0; j < 4; ++j) o[4 + j] = (short)f2bf(b[j]);
    ((short8*)xb)[i] = o;
}

// ---------------- weight transpose + convert ----------------
template <int MODE>
__global__ __launch_bounds__(256) void tq_kernel(const float* __restrict__ src,
                                                 unsigned short* __restrict__ dst,
                                                 int K, int N, size_t dstStrideE) {
    int e = blockIdx.z;
    src += (size_t)e * K * N;
    dst += (size_t)e * dstStrideE;
    __shared__ unsigned short tile[32][36];
    int t = threadIdx.x;
    int k0 = blockIdx.y * 32, n0 = blockIdx.x * 32;
    {
        int row = t >> 3, c4 = (t & 7) * 4;
        f32x4 v = *(const f32x4*)(src + (size_t)(k0 + row) * N + n0 + c4);
#pragma unroll
        for (int j = 0; j < 4; ++j) tile[row][c4 + j] = f2bf(v[j]);
    }
    __syncthreads();
    {
        int nn = t >> 3, kc = (t & 7) * 4;
        int n = n0 + nn;
        int r = (MODE == 0) ? n : ((n >> 4) * 32 + (MODE == 2 ? 16 : 0) + (n & 15));
        u16x4 o;
#pragma unroll
        for (int j = 0; j < 4; ++j) o[j] = tile[kc + j][nn];
        *(u16x4*)(dst + (size_t)r * K + k0 + kc) = o;
    }
}

// ================= 256x256 GEMM, deep pipeline =================
// LDS 160KB: A double-buffer [0,32K),[32K,64K); B triple-buffer 64K+{0,1,2}*32K.
// Per K-tile t: stage A(t+1) (4 loads, phA) and B(t+2) (2+2, phB/phC).
// One wait/tile: vmcnt(4) at phD (newest 4 = B(t+2)); vmcnt(0) for tail tiles.

#define STA4(base, kt) do { \
    gload16(gA[0][0] + (kt) * 64, (void*)(smem + (base) + ldsA[0][0])); \
    gload16(gA[0][1] + (kt) * 64, (void*)(smem + (base) + ldsA[0][1])); \
    gload16(gA[1][0] + (kt) * 64, (void*)(smem + (base) + ldsA[1][0])); \
    gload16(gA[1][1] + (kt) * 64, (void*)(smem + (base) + ldsA[1][1])); \
  } while (0)
#define STBU(base, kt, u) do { \
    gload16(gB[u][0] + (kt) * 64, (void*)(smem + (base) + ldsB[u][0])); \
    gload16(gB[u][1] + (kt) * 64, (void*)(smem + (base) + ldsB[u][1])); \
  } while (0)

#define RDA(base, MH) do { \
    _Pragma("unroll") \
    for (int m2 = 0; m2 < 4; ++m2) { \
      const char* bp = smem + (base) + (wm * 128 + (MH) * 64 + m2 * 16 + fr) * 128; \
      aF[m2][0] = *(const short8*)(bp + kA0); \
      aF[m2][1] = *(const short8*)(bp + kA1); \
    } } while (0)
#define RDB(dst, base, NH) do { \
    _Pragma("unroll") \
    for (int n2 = 0; n2 < 2; ++n2) { \
      const char* bp = smem + (base) + (wn * 64 + (NH) * 32 + n2 * 16 + fr) * 128; \
      dst[n2][0] = *(const short8*)(bp + kA0); \
      dst[n2][1] = *(const short8*)(bp + kA1); \
    } } while (0)

#define MM(MH, NH, BF) do { \
    __builtin_amdgcn_s_setprio(1); \
    _Pragma("unroll") \
    for (int m2 = 0; m2 < 4; ++m2) { \
      _Pragma("unroll") \
      for (int n2 = 0; n2 < 2; ++n2) { \
        acc[(MH) * 4 + m2][(NH) * 2 + n2] = __builtin_amdgcn_mfma_f32_16x16x32_bf16( \
            aF[m2][0], BF[n2][0], acc[(MH) * 4 + m2][(NH) * 2 + n2], 0, 0, 0); \
        acc[(MH) * 4 + m2][(NH) * 2 + n2] = __builtin_amdgcn_mfma_f32_16x16x32_bf16( \
            aF[m2][1], BF[n2][1], acc[(MH) * 4 + m2][(NH) * 2 + n2], 0, 0, 0); \
      } \
    } \
    __builtin_amdgcn_s_setprio(0); \
  } while (0)

#define BARMID do { \
    __builtin_amdgcn_s_barrier(); \
    asm volatile("s_waitcnt lgkmcnt(0)" ::: "memory"); \
    __builtin_amdgcn_sched_barrier(0); \
  } while (0)

template <int KIND>  // 0 shared-up, 1 routed-up, 2 shared-down splitK, 3 routed-down
__global__ __launch_bounds__(512, 2) void gemm8p(
    const unsigned short* __restrict__ A, const unsigned short* __restrict__ Ball,
    const int* __restrict__ cnt, const int* __restrict__ offs,
    const int* __restrict__ list, const float* __restrict__ cw,
    unsigned short* __restrict__ hout, float* __restrict__ fout,
    const int* __restrict__ table) {
    constexpr bool ROUTED = (KIND == 1 || KIND == 3);
    constexpr bool UP = (KIND <= 1);
    constexpr int K = (KIND <= 1) ? 2048 : 1024;
    constexpr int NT = K / 64;
    constexpr int ASTR = (KIND == 3) ? 1024 : 2048;
    constexpr int BSTR = (KIND == 3) ? 1024 : 2048;

    int bx, rb, e, M, obase;
    if constexpr (ROUTED) {
        int bid = blockIdx.x;
        int slot = bid >> 3;
        if (slot >= table[255]) return;
        bx = bid & 7;
        e = table[slot];
        rb = table[128 + slot];
        M = cnt[e];
        obase = offs[e];
    } else {
        bx = blockIdx.x; rb = blockIdx.y * 256; e = 0; M = T_TOK; obase = 0;
    }
    const int kb = (KIND == 2) ? blockIdx.z * 1024 : 0;
    const unsigned short* Bp = Ball +
        (KIND == 1 ? (size_t)e * 2048 * 2048 : KIND == 3 ? (size_t)e * 2048 * 1024 : 0);

    extern __shared__ char smem[];

    const int tid = threadIdx.x;
    const int lane = tid & 63, wid = tid >> 6;
    const int wm = wid >> 2, wn = wid & 3;
    const int fr = lane & 15, fq = lane >> 4;
    const int swz = (fr & 7) << 4;
    const int kA0 = (fq * 16) ^ swz;
    const int kA1 = (64 + fq * 16) ^ swz;

    int ldsA[2][2], ldsB[2][2];
    const unsigned short* gA[2][2];
    const unsigned short* gB[2][2];
#pragma unroll
    for (int u = 0; u < 2; ++u)
#pragma unroll
        for (int i = 0; i < 2; ++i) {
            int rowA = i * 128 + u * 64 + (tid >> 3);
            int kcA = (tid & 7) ^ (rowA & 7);
            ldsA[u][i] = i * 16384 + u * 8192 + tid * 16;
            int gr = rb + rowA;
            int cr = (gr < M) ? gr : (M - 1);
            size_t arow;
            if (KIND == 1)      arow = (size_t)list[e * T_TOK + cr];
            else if (KIND == 3) arow = (size_t)(obase + cr);
            else                arow = (size_t)gr;
            gA[u][i] = A + arow * ASTR + kb + kcA * 8;

            int s = (tid >> 8) + 2 * i;
            int rowB = s * 64 + u * 32 + ((tid >> 3) & 31);
            int kcB = (tid & 7) ^ (rowB & 7);
            ldsB[u][i] = s * 8192 + u * 4096 + (tid & 255) * 16;
            gB[u][i] = Bp + (size_t)(bx * 256 + rowB) * BSTR + kb + kcB * 8;
        }

    f32x4 acc[8][4];
#pragma unroll
    for (int m = 0; m < 8; ++m)
#pragma unroll
        for (int n = 0; n < 4; ++n) acc[m][n] = (f32x4)0.f;

    short8 aF[4][2], bF0[2][2], bF1[2][2];

    // prologue: B(0)->b0, B(1)->b1, A(0)->a0
    STBU(65536, 0, 0); STBU(65536, 0, 1);
    STBU(65536 + 32768, 1, 0); STBU(65536 + 32768, 1, 1);
    STA4(0, 0);
    asm volatile("s_waitcnt vmcnt(0)" ::: "memory");
    __builtin_amdgcn_s_barrier();

    int bB = 0, bB2 = 2;
    for (int t = 0; t < NT; ++t) {
        const int baseA = (t & 1) * 32768;
        const int baseAn = ((t + 1) & 1) * 32768;
        const int baseB = 65536 + bB * 32768;
        const int baseBn = 65536 + bB2 * 32768;
        const bool moreA = (t + 1 < NT);
        const bool moreB = (t + 2 < NT);
        // phase A
        RDA(baseA, 0); RDB(bF0, baseB, 0);
        if (moreA) STA4(baseAn, t + 1);
        BARMID;
        MM(0, 0, bF0);
        __builtin_amdgcn_s_barrier();
        // phase B
        RDB(bF1, baseB, 1);
        if (moreB) STBU(baseBn, t + 2, 0);
        BARMID;
        MM(0, 1, bF1);
        __builtin_amdgcn_s_barrier();
        // phase C
        RDA(baseA, 1);
        if (moreB) STBU(baseBn, t + 2, 1);
        BARMID;
        MM(1, 1, bF1);
        __builtin_amdgcn_s_barrier();
        // phase D
        MM(1, 0, bF0);
        if (moreB) { asm volatile("s_waitcnt vmcnt(4)" ::: "memory"); }
        else       { asm volatile("s_waitcnt vmcnt(0)" ::: "memory"); }
        __builtin_amdgcn_s_barrier();
        bB = (bB == 2) ? 0 : bB + 1;
        bB2 = (bB2 == 2) ? 0 : bB2 + 1;
    }

    // epilogue
    if constexpr (UP) {
        constexpr int LDO = (KIND == 1) ? NI : NSH;
#pragma unroll
        for (int mf = 0; mf < 8; ++mf)
#pragma unroll
            for (int q = 0; q < 4; ++q) {
                int gr = rb + wm * 128 + mf * 16 + fq * 4 + q;
                if (gr < M) {
                    float coef = 1.f;
                    if constexpr (KIND == 1) coef = cw[e * T_TOK + gr];
                    size_t orow = (size_t)(obase + gr) * LDO;
#pragma unroll
                    for (int nfp = 0; nfp < 2; ++nfp) {
                        float c1 = acc[mf][2 * nfp][q], c3 = acc[mf][2 * nfp + 1][q];
                        float h = c1 / (1.f + __expf(-c1)) * c3 * coef;
                        int ncol = (bx * 8 + wn * 2 + nfp) * 16 + fr;
                        hout[orow + ncol] = f2bf(h);
                    }
                }
            }
    } else {
#pragma unroll
        for (int mf = 0; mf < 8; ++mf)
#pragma unroll
            for (int q = 0; q < 4; ++q) {
                int gr = rb + wm * 128 + mf * 16 + fq * 4 + q;
                if (gr < M) {
                    int orow = (KIND == 3) ? list[e * T_TOK + gr] : gr;
#pragma unroll
                    for (int nf = 0; nf < 4; ++nf) {
                        int col = bx * 256 + wn * 64 + nf * 16 + fr;
                        atomicAdd(fout + (size_t)orow * DIMD + col, acc[mf][nf][q]);
                    }
                }
            }
    }
}

extern "C" void kernel_launch(void* const* d_in, const int* in_sizes, int n_in,
                              void* d_out, int out_size, void* d_ws, size_t ws_size,
                              hipStream_t stream) {
    const float* x   = (const float*)d_in[0];
    const float* gw  = (const float*)d_in[1];
    const float* w1  = (const float*)d_in[2];
    const float* w2  = (const float*)d_in[3];
    const float* w3  = (const float*)d_in[4];
    const float* ws1 = (const float*)d_in[5];
    const float* ws2 = (const float*)d_in[6];
    const float* ws3 = (const float*)d_in[7];
    float* out = (float*)d_out;

    char* p = (char*)d_ws;
    unsigned short* xb   = (unsigned short*)p; p += (size_t)T_TOK * DIMD * 2;
    unsigned short* hs   = (unsigned short*)p; p += (size_t)T_TOK * NSH * 2;
    unsigned short* hbuf = (unsigned short*)p; p += (size_t)T_TOK * TOPK * NI * 2;
    unsigned short* upT  = (unsigned short*)p; p += (size_t)NEXP * 2048 * DIMD * 2;
    unsigned short* w2T  = (unsigned short*)p; p += (size_t)NEXP * DIMD * NI * 2;
    unsigned short* upsT = (unsigned short*)p; p += (size_t)2 * NSH * DIMD * 2;
    unsigned short* ws2T = (unsigned short*)p; p += (size_t)DIMD * NSH * 2;
    float* cw = (float*)p;                     p += (size_t)NEXP * T_TOK * 4;
    int* list = (int*)p;                       p += (size_t)NEXP * T_TOK * 4;
    int* cnt = (int*)p;                        p += 256;
    int* offs = (int*)p;                       p += 256;
    int* table = (int*)p;                      p += 1024;
    if ((size_t)(p - (char*)d_ws) > ws_size) return;

    hipFuncSetAttribute((const void*)&gemm8p<0>, hipFuncAttributeMaxDynamicSharedMemorySize, 163840);
    hipFuncSetAttribute((const void*)&gemm8p<1>, hipFuncAttributeMaxDynamicSharedMemorySize, 163840);
    hipFuncSetAttribute((const void*)&gemm8p<2>, hipFuncAttributeMaxDynamicSharedMemorySize, 163840);
    hipFuncSetAttribute((const void*)&gemm8p<3>, hipFuncAttributeMaxDynamicSharedMemorySize, 163840);

    hipMemsetAsync(cnt, 0, 64, stream);
    hipMemsetAsync(out, 0, (size_t)out_size * 4, stream);
    gate_kernel<<<T_TOK, 64, 0, stream>>>(x, gw, cnt, list, cw);
    scan_kernel<<<1, 64, 0, stream>>>(cnt, offs, table);
    cvt_kernel<<<(T_TOK * DIMD / 8) / 256, 256, 0, stream>>>(x, xb);

    tq_kernel<1><<<dim3(NI / 32, DIMD / 32, NEXP), 256, 0, stream>>>(w1, upT, DIMD, NI, (size_t)2048 * DIMD);
    tq_kernel<2><<<dim3(NI / 32, DIMD / 32, NEXP), 256, 0, stream>>>(w3, upT, DIMD, NI, (size_t)2048 * DIMD);
    tq_kernel<1><<<dim3(NSH / 32, DIMD / 32, 1), 256, 0, stream>>>(ws1, upsT, DIMD, NSH, 0);
    tq_kernel<2><<<dim3(NSH / 32, DIMD / 32, 1), 256, 0, stream>>>(ws3, upsT, DIMD, NSH, 0);
    tq_kernel<0><<<dim3(DIMD / 32, NI / 32, NEXP), 256, 0, stream>>>(w2, w2T, NI, DIMD, (size_t)DIMD * NI);
    tq_kernel<0><<<dim3(DIMD / 32, NSH / 32, 1), 256, 0, stream>>>(ws2, ws2T, NSH, DIMD, 0);

    gemm8p<0><<<dim3(16, 16, 1), 512, 163840, stream>>>(
        xb, upsT, nullptr, nullptr, nullptr, nullptr, hs, nullptr, nullptr);
    gemm8p<2><<<dim3(8, 16, 2), 512, 163840, stream>>>(
        hs, ws2T, nullptr, nullptr, nullptr, nullptr, nullptr, out, nullptr);
    gemm8p<1><<<640, 512, 163840, stream>>>(
        xb, upT, cnt, offs, list, cw, hbuf, nullptr, table);
    gemm8p<3><<<640, 512, 163840, stream>>>(
        hbuf, w2T, cnt, offs, list, nullptr, nullptr, out, table);
}